// Round 9
// baseline (130.946 us; speedup 1.0000x reference)
//
#include <hip/hip_runtime.h>

#define GRID 32
#define NT 48
#define BLK 256
#define SPLIT 16                 // threads per point; each handles 3 t-rows
#define PPB (BLK / SPLIT)        // 16 points per block

typedef float v2f __attribute__((ext_vector_type(2)));

// Per-edge packed info: bits [0]=base_x, [1]=base_y, [2]=base_z, [4:3]=axis.
#define EDGE_PACK ( (0ULL<<0) | (9ULL<<5) | (2ULL<<10) | (8ULL<<15) | \
                    (4ULL<<20) | (13ULL<<25) | (6ULL<<30) | (12ULL<<35) | \
                    (16ULL<<40) | (17ULL<<45) | (19ULL<<50) | (18ULL<<55) )

__device__ __forceinline__ int cell_of(float p) {
    return min(max((int)floorf(p), 0), GRID - 1);
}

// Region-select cascade (reference `where` order, later wins) -> (nv, nw, r).
// Scalar, per triangle; bit-identical to the r8-verified sequence.
// nv merge: (c_ac|c_c|c_a)->0 safe (conflicts only when a==b bitwise, where
// both branches give identical q).
__device__ __forceinline__ void cascade(float d1, float d2, float d3, float d4,
                                        float d5, float d6, float va, float vb,
                                        float vc, float d43, float d56,
                                        float& nv, float& nw, float& r) {
    bool c_bc = (va <= 0.0f) & (d43 >= 0.0f) & (d56 >= 0.0f);
    bool c_ac = (vb <= 0.0f) & (d2 >= 0.0f) & (d6 <= 0.0f);
    bool c_c  = (d6 >= 0.0f) & (d5 <= d6);
    bool c_ab = (vc <= 0.0f) & (d1 >= 0.0f) & (d3 <= 0.0f);
    bool c_b  = (d3 >= 0.0f) & (d4 <= d3);
    bool c_a  = (d1 <= 0.0f) & (d2 <= 0.0f);

    float den = va + vb + vc;
    den = c_bc ? (d43 + d56) : den;
    den = c_ac ? (d2 - d6)   : den;
    den = c_c  ? 1.0f        : den;
    den = c_ab ? (d1 - d3)   : den;
    den = (c_b | c_a) ? 1.0f : den;
    den = (fabsf(den) > 1e-12f) ? den : 1e-12f;
    r = __builtin_amdgcn_rcpf(den);

    nw = vc;
    nw = c_bc ? d43  : nw;
    nw = c_ac ? d2   : nw;
    nw = c_c  ? 1.0f : nw;
    nw = (c_ab | c_b | c_a) ? 0.0f : nw;

    nv = vb;
    nv = c_bc ? (den - d43)        : nv;  // == d56 sane / eps-clamp -> v=1
    nv = (c_ac | c_c | c_a) ? 0.0f : nv;
    nv = c_ab ? d1   : nv;
    nv = c_b  ? 1.0f : nv;
}

// TWO triangles at once: heavy arithmetic in <2 x float> so the backend can
// emit v_pk_{mul,add,fma}_f32 (VOP3P packed-f32, gfx90a+); condition inputs
// computed contract-OFF in numpy's evaluation order per half (r5 lesson),
// cascade per half scalar (halves are individually addressable VGPRs).
__device__ __forceinline__ v2f tri2_dist_sq(
    v2f Ax, v2f Ay, v2f Az, v2f Bx, v2f By, v2f Bz, v2f Cx, v2f Cy, v2f Cz) {
    v2f abx = Ax - Bx, aby = Ay - By, abz = Az - Bz;
    v2f acx = Ax - Cx, acy = Ay - Cy, acz = Az - Cz;
    v2f d1, d2, d3, d4, d5, d6, va, vb, vc, d43, d56;
    {
#pragma clang fp contract(off)
        d1 = (abx * Ax + aby * Ay) + abz * Az;
        d2 = (acx * Ax + acy * Ay) + acz * Az;
        d3 = (abx * Bx + aby * By) + abz * Bz;
        d4 = (acx * Bx + acy * By) + acz * Bz;
        d5 = (abx * Cx + aby * Cy) + abz * Cz;
        d6 = (acx * Cx + acy * Cy) + acz * Cz;
        vc = d1 * d4 - d3 * d2;
        vb = d5 * d2 - d1 * d6;
        va = d3 * d6 - d5 * d4;
        d43 = d4 - d3;
        d56 = d5 - d6;
    }
    float nv0, nw0, r0, nv1, nw1, r1;
    cascade(d1.x, d2.x, d3.x, d4.x, d5.x, d6.x, va.x, vb.x, vc.x, d43.x, d56.x,
            nv0, nw0, r0);
    cascade(d1.y, d2.y, d3.y, d4.y, d5.y, d6.y, va.y, vb.y, vc.y, d43.y, d56.y,
            nv1, nw1, r1);
    v2f v = (v2f){nv0 * r0, nv1 * r1};
    v2f w = (v2f){nw0 * r0, nw1 * r1};
    v2f dx = Ax - abx * v - acx * w;
    v2f dy = Ay - aby * v - acy * w;
    v2f dz = Az - abz * v - acz * w;
    return dx * dx + dy * dy + dz * dz;
}

// Scalar single-tri version (r8-verified), for the 9th triangle.
__device__ __forceinline__ float tri_dist_sq(float4 A, float4 B, float4 C) {
    float abx = A.x - B.x, aby = A.y - B.y, abz = A.z - B.z;
    float acx = A.x - C.x, acy = A.y - C.y, acz = A.z - C.z;
    float d1, d2, d3, d4, d5, d6, va, vb, vc, d43, d56;
    {
#pragma clang fp contract(off)
        d1 = (abx * A.x + aby * A.y) + abz * A.z;
        d2 = (acx * A.x + acy * A.y) + acz * A.z;
        d3 = (abx * B.x + aby * B.y) + abz * B.z;
        d4 = (acx * B.x + acy * B.y) + acz * B.z;
        d5 = (abx * C.x + aby * C.y) + abz * C.z;
        d6 = (acx * C.x + acy * C.y) + acz * C.z;
        vc = d1 * d4 - d3 * d2;
        vb = d5 * d2 - d1 * d6;
        va = d3 * d6 - d5 * d4;
        d43 = d4 - d3;
        d56 = d5 - d6;
    }
    float nv, nw, r;
    cascade(d1, d2, d3, d4, d5, d6, va, vb, vc, d43, d56, nv, nw, r);
    float v = nv * r;
    float w = nw * r;
    float dx = A.x - abx * v - acx * w;
    float dy = A.y - aby * v - acy * w;
    float dz = A.z - abz * v - acz * w;
    return dx * dx + dy * dy + dz * dz;
}

__global__ __launch_bounds__(BLK) void ptd_kernel(
    const float* __restrict__ offset,     // (3,33,33,33)
    const float* __restrict__ points,     // (N,3)
    const int*   __restrict__ tri_table,  // (48,3,3)
    float*       __restrict__ out,        // (32768,48)
    int n)
{
    // Per-point rows of p-relative edge vertices, stride 13 float4s.
    __shared__ float4 v_s[PPB * 13];
    // Packed tri indices: row[grp][c], c<9: i0|i1<<8|i2<<16 of (t=grp*3+c/3, k=c%3).
    __shared__ int t_tab4[16][12];

    const int tid = threadIdx.x;
    const int g   = blockIdx.x * BLK + tid;
    const int pt  = g >> 4;               // SPLIT=16
    const int grp = tid & 15;
    const int pl  = tid >> 4;
    const bool active = (pt < n);

    if (tid < 144) {
        int i0 = tri_table[tid * 3 + 0];
        int i1 = tri_table[tid * 3 + 1];
        int i2 = tri_table[tid * 3 + 2];
        t_tab4[tid / 9][tid % 9] = i0 | (i1 << 8) | (i2 << 16);
    }

    int cx = 0, cy = 0, cz = 0;
    if (active) {
        float px = points[pt * 3 + 0];
        float py = points[pt * 3 + 1];
        float pz = points[pt * 3 + 2];
        cx = cell_of(px); cy = cell_of(py); cz = cell_of(pz);
        if (grp < 12) {
            float lx = px - (float)cx, ly = py - (float)cy, lz = pz - (float)cz;
            unsigned nib = (unsigned)(EDGE_PACK >> (5 * grp)) & 31u;
            int gx = cx + (int)(nib & 1u);
            int gy = cy + (int)((nib >> 1) & 1u);
            int gz = cz + (int)((nib >> 2) & 1u);
            int ax = (int)(nib >> 3);
            float t = offset[((ax * 33 + gx) * 33 + gy) * 33 + gz];
            float vx = (ax == 0) ? t : (float)(nib & 1u);
            float vy = (ax == 1) ? t : (float)((nib >> 1) & 1u);
            float vz = (ax == 2) ? t : (float)((nib >> 2) & 1u);
            v_s[pl * 13 + grp] = make_float4(lx - vx, ly - vy, lz - vz, 0.0f);
        }
    }
    __syncthreads();

    if (!active) return;

    const int* tp = &t_tab4[grp][0];
    int4 qa = *(const int4*)tp;
    int4 qb = *(const int4*)(tp + 4);
    int pk[9] = {qa.x, qa.y, qa.z, qa.w, qb.x, qb.y, qb.z, qb.w, tp[8]};

    const float4* vrow = &v_s[pl * 13];
    float* outp = out + ((((cx * GRID) + cy) * GRID + cz) * NT) + grp * 3;

    float dall[9];
#pragma unroll
    for (int pr = 0; pr < 4; pr++) {
        int e0 = pk[2 * pr + 0];
        int e1 = pk[2 * pr + 1];
        float4 A0 = vrow[e0 & 255], B0 = vrow[(e0 >> 8) & 255], C0 = vrow[(e0 >> 16) & 255];
        float4 A1 = vrow[e1 & 255], B1 = vrow[(e1 >> 8) & 255], C1 = vrow[(e1 >> 16) & 255];
        v2f d = tri2_dist_sq((v2f){A0.x, A1.x}, (v2f){A0.y, A1.y}, (v2f){A0.z, A1.z},
                             (v2f){B0.x, B1.x}, (v2f){B0.y, B1.y}, (v2f){B0.z, B1.z},
                             (v2f){C0.x, C1.x}, (v2f){C0.y, C1.y}, (v2f){C0.z, C1.z});
        dall[2 * pr + 0] = d.x;
        dall[2 * pr + 1] = d.y;
    }
    {
        int e8 = pk[8];
        dall[8] = tri_dist_sq(vrow[e8 & 255], vrow[(e8 >> 8) & 255], vrow[(e8 >> 16) & 255]);
    }

    float m0 = fminf(fminf(dall[0], dall[1]), dall[2]);
    float m1 = fminf(fminf(dall[3], dall[4]), dall[5]);
    float m2 = fminf(fminf(dall[6], dall[7]), dall[8]);
    atomicAdd(&outp[0], m0);
    atomicAdd(&outp[1], m1);
    atomicAdd(&outp[2], m2);
}

extern "C" void kernel_launch(void* const* d_in, const int* in_sizes, int n_in,
                              void* d_out, int out_size, void* d_ws, size_t ws_size,
                              hipStream_t stream) {
    const float* offset    = (const float*)d_in[0];
    const float* points    = (const float*)d_in[1];
    const int*   tri_table = (const int*)d_in[2];
    float* out = (float*)d_out;
    int n = in_sizes[1] / 3;  // 131072 points

    // Output accumulated via atomics; harness poisons d_out with 0xAA.
    hipMemsetAsync(d_out, 0, (size_t)out_size * sizeof(float), stream);

    long total = (long)n * SPLIT;
    int blocks = (int)((total + BLK - 1) / BLK);
    ptd_kernel<<<blocks, BLK, 0, stream>>>(offset, points, tri_table, out, n);
}